// Round 1
// baseline (255.609 us; speedup 1.0000x reference)
//
#include <hip/hip_runtime.h>
#include <hip/hip_bf16.h>

// Problem: B=4, C=8, N=M=K=1024, DX=1.
// z1[b,c] = W_b (N x M) @ Z_{b,c} (M x K);  z2[b,c] = z1 @ z1^T (N x N)
// W[b][n][m] = exp(-512 * (x[b][n] - xz[m])^2)   (exp(2*log_scale) = 1/1024)
// d_out = [ xz (1024 f32) | z2 (4*8*1024*1024 f32) ]
// ws: W bf16 (8 MB) | Zt bf16 (64 MB, [b][c][k][m]) | z1 bf16 (64 MB, [b][c][n][k])

typedef __attribute__((ext_vector_type(8))) unsigned short u16x8;
typedef __attribute__((ext_vector_type(8))) __bf16 bf16x8;
typedef __attribute__((ext_vector_type(4))) float f32x4;

typedef __attribute__((address_space(1))) void gvoid;
typedef __attribute__((address_space(3))) void svoid;
#define GLDS(g, s) __builtin_amdgcn_global_load_lds((gvoid*)(g), (svoid*)(s), 16, 0, 0)

__device__ __forceinline__ unsigned short f2bf(float f) {
  unsigned int u = __builtin_bit_cast(unsigned int, f);
  u += 0x7fffu + ((u >> 16) & 1u);   // round-to-nearest-even
  return (unsigned short)(u >> 16);
}

__device__ __forceinline__ bf16x8 as_bf16x8(u16x8 v) {
  return __builtin_bit_cast(bf16x8, v);
}

// ---------------- W = exp(-0.5*d^2/exp(2*ls)) as bf16 -----------------------
__global__ void weights_kernel(const float* __restrict__ xz, const float* __restrict__ x,
                               const float* __restrict__ ls, unsigned short* __restrict__ W) {
  int bn = blockIdx.x;                       // b*1024 + n
  float xv = x[bn];
  float coef = -0.5f * __expf(-2.0f * ls[0]);
  unsigned short* Wrow = W + (size_t)bn * 1024;
  #pragma unroll
  for (int i = 0; i < 4; ++i) {
    int m = threadIdx.x + i * 256;
    float d = xv - xz[m];
    Wrow[m] = f2bf(__expf(coef * d * d));
  }
}

// ---------------- Zt[b][c][k][m] = bf16(Z[b][c][m][k]) ----------------------
__global__ void transpose_kernel(const float* __restrict__ Z, unsigned short* __restrict__ Zt) {
  __shared__ float tile[64][65];
  int bc = blockIdx.z;
  const float* Zp = Z + ((size_t)bc << 20);
  unsigned short* Ztp = Zt + ((size_t)bc << 20);
  int m0 = blockIdx.x * 64, k0 = blockIdx.y * 64;
  int tx = threadIdx.x & 63, tg = threadIdx.x >> 6;   // tg: 0..3
  #pragma unroll
  for (int i = 0; i < 16; ++i) {
    int ml = tg + i * 4;
    tile[ml][tx] = Zp[(size_t)(m0 + ml) * 1024 + k0 + tx];
  }
  __syncthreads();
  int tx2 = (threadIdx.x & 31) * 2, kg = threadIdx.x >> 5;  // kg: 0..7
  #pragma unroll
  for (int i = 0; i < 8; ++i) {
    int kl = kg + i * 8;
    ushort2 v;
    v.x = f2bf(tile[tx2][kl]);
    v.y = f2bf(tile[tx2 + 1][kl]);
    *(ushort2*)&Ztp[(size_t)(k0 + kl) * 1024 + m0 + tx2] = v;
  }
}

// ---------------- NT bf16 GEMM: C = A(1024xK) * B(1024xK)^T -----------------
// 128x128 tile, BK=32, 4 waves (2x2 of 64x64), 16x16x32 bf16 MFMA.
// A_PER_B: A batch stride is per-b (W shared across c); else per-bc.
template<bool OUT_BF16, bool A_PER_B>
__global__ __launch_bounds__(256) void gemm_nt(const unsigned short* __restrict__ A,
                                               const unsigned short* __restrict__ B,
                                               unsigned short* __restrict__ Cbf,
                                               float* __restrict__ Cf) {
  __shared__ unsigned short As[128 * 32];   // [row][k] row-major, 8 KB
  __shared__ unsigned short Bs[128 * 32];
  int bc = blockIdx.z;
  const unsigned short* Ap = A + ((size_t)(A_PER_B ? (bc >> 3) : bc) << 20);
  const unsigned short* Bp = B + ((size_t)bc << 20);
  int tid = threadIdx.x;
  int wave = tid >> 6, lane = tid & 63;
  int wr = wave >> 1, wc = wave & 1;
  int la = lane & 15, ha = lane >> 4;
  f32x4 acc[4][4] = {};

  // staging: lane covers LDS bytes base + lane*16; row = r*64 + tid/4, col8 = (tid&3)*8
  const int rA = blockIdx.x * 128 + (tid >> 2);
  const int rB = blockIdx.y * 128 + (tid >> 2);
  const int c8 = (tid & 3) * 8;
  const unsigned short* gA0 = Ap + (size_t)rA * 1024 + c8;
  const unsigned short* gA1 = gA0 + (size_t)64 * 1024;
  const unsigned short* gB0 = Bp + (size_t)rB * 1024 + c8;
  const unsigned short* gB1 = gB0 + (size_t)64 * 1024;
  unsigned short* sA = &As[wave * 512];
  unsigned short* sB = &Bs[wave * 512];

  for (int kt = 0; kt < 1024; kt += 32) {
    GLDS(gA0 + kt, sA);
    GLDS(gA1 + kt, sA + 2048);
    GLDS(gB0 + kt, sB);
    GLDS(gB1 + kt, sB + 2048);
    __syncthreads();                       // drains vmcnt before barrier
    u16x8 af[4], bfr[4];
    #pragma unroll
    for (int m = 0; m < 4; ++m)
      af[m] = *(const u16x8*)&As[(wr * 64 + m * 16 + la) * 32 + ha * 8];
    #pragma unroll
    for (int n = 0; n < 4; ++n)
      bfr[n] = *(const u16x8*)&Bs[(wc * 64 + n * 16 + la) * 32 + ha * 8];
    #pragma unroll
    for (int m = 0; m < 4; ++m)
      #pragma unroll
      for (int n = 0; n < 4; ++n)
        acc[m][n] = __builtin_amdgcn_mfma_f32_16x16x32_bf16(
            as_bf16x8(af[m]), as_bf16x8(bfr[n]), acc[m][n], 0, 0, 0);
    __syncthreads();                       // LDS consumed before next stage
  }

  // epilogue: C/D layout col = lane&15, row = (lane>>4)*4 + j   [m89-verified]
  size_t cbase = (size_t)bc << 20;
  #pragma unroll
  for (int m = 0; m < 4; ++m) {
    int row0 = blockIdx.x * 128 + wr * 64 + m * 16 + ha * 4;
    #pragma unroll
    for (int n = 0; n < 4; ++n) {
      int col = blockIdx.y * 128 + wc * 64 + n * 16 + la;
      #pragma unroll
      for (int j = 0; j < 4; ++j) {
        size_t idx = cbase + (size_t)(row0 + j) * 1024 + col;
        if (OUT_BF16) Cbf[idx] = f2bf(acc[m][n][j]);
        else          Cf[idx]  = acc[m][n][j];
      }
    }
  }
}

extern "C" void kernel_launch(void* const* d_in, const int* in_sizes, int n_in,
                              void* d_out, int out_size, void* d_ws, size_t ws_size,
                              hipStream_t stream) {
  const float* xz = (const float*)d_in[0];   // (1024, 1)
  const float* z  = (const float*)d_in[1];   // (4, 8, 1024, 1024)
  const float* x  = (const float*)d_in[2];   // (4, 1024, 1)
  const float* ls = (const float*)d_in[3];   // scalar
  float* out = (float*)d_out;

  unsigned short* W  = (unsigned short*)d_ws;          // 4M elems (8 MB)
  unsigned short* Zt = W + ((size_t)4 << 20);          // 32M elems (64 MB)
  unsigned short* z1 = Zt + ((size_t)32 << 20);        // 32M elems (64 MB)

  hipMemcpyAsync(out, xz, 1024 * sizeof(float), hipMemcpyDeviceToDevice, stream);
  weights_kernel<<<4096, 256, 0, stream>>>(xz, x, ls, W);
  transpose_kernel<<<dim3(16, 16, 32), 256, 0, stream>>>(z, Zt);
  gemm_nt<true,  true ><<<dim3(8, 8, 32), 256, 0, stream>>>(W,  Zt, z1, nullptr);
  gemm_nt<false, false><<<dim3(8, 8, 32), 256, 0, stream>>>(z1, z1, nullptr, out + 1024);
}

// Round 2
// 187.034 us; speedup vs baseline: 1.3666x; 1.3666x over previous
//
#include <hip/hip_runtime.h>
#include <hip/hip_bf16.h>

// Problem: B=4, C=8, N=M=K=1024, DX=1.
// z1[b,c] = W_b (N x M) @ Z_{b,c} (M x K);  z2[b,c] = z1 @ z1^T (symmetric)
// W[b][n][m] = exp(-512 * (x[b][n] - xz[m])^2)
// d_out = [ xz (1024 f32) | z2 (4*8*1024*1024 f32) ]
// ws: W bf16 (8 MB) | Zt bf16 (64 MB, [b][c][k][m]) | z1 bf16 (64 MB, [b][c][n][k])

typedef __attribute__((ext_vector_type(8))) unsigned short u16x8;
typedef __attribute__((ext_vector_type(8))) __bf16 bf16x8;
typedef __attribute__((ext_vector_type(4))) float f32x4;

typedef __attribute__((address_space(1))) void gvoid;
typedef __attribute__((address_space(3))) void svoid;
#define GLDS(g, s) __builtin_amdgcn_global_load_lds((gvoid*)(g), (svoid*)(s), 16, 0, 0)

__device__ __forceinline__ unsigned short f2bf(float f) {
  unsigned int u = __builtin_bit_cast(unsigned int, f);
  u += 0x7fffu + ((u >> 16) & 1u);   // round-to-nearest-even
  return (unsigned short)(u >> 16);
}

__device__ __forceinline__ bf16x8 as_bf16x8(u16x8 v) {
  return __builtin_bit_cast(bf16x8, v);
}

// ---------------- W = exp(-0.5*d^2/exp(2*ls)) as bf16 -----------------------
__global__ void weights_kernel(const float* __restrict__ xz, const float* __restrict__ x,
                               const float* __restrict__ ls, unsigned short* __restrict__ W) {
  int bn = blockIdx.x;
  float xv = x[bn];
  float coef = -0.5f * __expf(-2.0f * ls[0]);
  unsigned short* Wrow = W + (size_t)bn * 1024;
  #pragma unroll
  for (int i = 0; i < 4; ++i) {
    int m = threadIdx.x + i * 256;
    float d = xv - xz[m];
    Wrow[m] = f2bf(__expf(coef * d * d));
  }
}

// ---------------- Zt[b][c][k][m] = bf16(Z[b][c][m][k]) ----------------------
__global__ void transpose_kernel(const float* __restrict__ Z, unsigned short* __restrict__ Zt) {
  __shared__ float tile[64][65];
  int bc = blockIdx.z;
  const float* Zp = Z + ((size_t)bc << 20);
  unsigned short* Ztp = Zt + ((size_t)bc << 20);
  int m0 = blockIdx.x * 64, k0 = blockIdx.y * 64;
  int tx = threadIdx.x & 63, tg = threadIdx.x >> 6;
  #pragma unroll
  for (int i = 0; i < 16; ++i) {
    int ml = tg + i * 4;
    tile[ml][tx] = Zp[(size_t)(m0 + ml) * 1024 + k0 + tx];
  }
  __syncthreads();
  int tx2 = (threadIdx.x & 31) * 2, kg = threadIdx.x >> 5;
  #pragma unroll
  for (int i = 0; i < 8; ++i) {
    int kl = kg + i * 8;
    ushort2 v;
    v.x = f2bf(tile[tx2][kl]);
    v.y = f2bf(tile[tx2 + 1][kl]);
    *(ushort2*)&Ztp[(size_t)(k0 + kl) * 1024 + m0 + tx2] = v;
  }
}

// ---------------- NT bf16 GEMM: C = A(1024xK) * B(1024xK)^T -----------------
// 128x128 tile, BK=32, 4 waves (2x2 of 64x64), 16x16x32 bf16 MFMA.
// Triple-buffered LDS, stage 2 tiles ahead, counted vmcnt(4), raw s_barrier.
// SYMM: only upper-triangle 128-tiles (i<=j); mirror via LDS band transpose.
template<int TPB, bool OUT_BF16, bool A_PER_B, bool SYMM>
__global__ __launch_bounds__(256) void gemm_nt(const unsigned short* __restrict__ A,
                                               const unsigned short* __restrict__ B,
                                               unsigned short* __restrict__ Cbf,
                                               float* __restrict__ Cf) {
  __shared__ __align__(16) char smem[49152];   // A: 3x8KB @0, B: 3x8KB @24576

  // XCD-chunked bijective swizzle (nwg % 8 == 0): same-bc blocks share an XCD's L2.
  const int chunk = (TPB * 32) >> 3;
  int w = ((int)blockIdx.x & 7) * chunk + ((int)blockIdx.x >> 3);
  int bc = w / TPB;
  int t  = w % TPB;
  int bi, bj;
  if (SYMM) {
    bi = 0;
    while (t >= 8 - bi) { t -= 8 - bi; ++bi; }
    bj = bi + t;                       // i <= j
  } else {
    bj = t >> 3; bi = t & 7;           // consecutive blocks share the B panel
  }

  const unsigned short* Ap = A + ((size_t)(A_PER_B ? (bc >> 3) : bc) << 20);
  const unsigned short* Bp = B + ((size_t)bc << 20);
  const int tid = threadIdx.x;
  const int wave = tid >> 6, lane = tid & 63;
  const int wr = wave >> 1, wc = wave & 1;
  const int la = lane & 15, ha = lane >> 4;
  f32x4 acc[4][4] = {};

  // staging addresses: thread covers row tid>>2, 8-col chunk (tid&3)*8
  const int c8 = (tid & 3) * 8;
  const unsigned short* gA0 = Ap + (size_t)(bi * 128 + (tid >> 2)) * 1024 + c8;
  const unsigned short* gA1 = gA0 + (size_t)64 * 1024;
  const unsigned short* gB0 = Bp + (size_t)(bj * 128 + (tid >> 2)) * 1024 + c8;
  const unsigned short* gB1 = gB0 + (size_t)64 * 1024;

  auto stage = [&](int slot, int kt) {
    unsigned short* dA = (unsigned short*)(smem + slot * 8192) + wave * 512;
    unsigned short* dB = (unsigned short*)(smem + 24576 + slot * 8192) + wave * 512;
    GLDS(gA0 + kt, dA); GLDS(gA1 + kt, dA + 2048);
    GLDS(gB0 + kt, dB); GLDS(gB1 + kt, dB + 2048);
  };

  // prologue: tiles 0,1 in flight; wait tile 0 (4 loads outstanding = tile 1)
  stage(0, 0);
  stage(1, 32);
  asm volatile("s_waitcnt vmcnt(4)" ::: "memory");
  __builtin_amdgcn_s_barrier();

  int sl0 = 0, sl1 = 1, sl2 = 2;
  for (int t2 = 0; t2 < 32; ++t2) {
    if (t2 < 30) stage(sl2, (t2 + 2) * 32);
    const unsigned short* rA = (const unsigned short*)(smem + sl0 * 8192);
    const unsigned short* rB = (const unsigned short*)(smem + 24576 + sl0 * 8192);
    u16x8 af[4], bfr[4];
    #pragma unroll
    for (int m = 0; m < 4; ++m)
      af[m] = *(const u16x8*)&rA[(wr * 64 + m * 16 + la) * 32 + ha * 8];
    #pragma unroll
    for (int n = 0; n < 4; ++n)
      bfr[n] = *(const u16x8*)&rB[(wc * 64 + n * 16 + la) * 32 + ha * 8];
    #pragma unroll
    for (int m = 0; m < 4; ++m)
      #pragma unroll
      for (int n = 0; n < 4; ++n)
        acc[m][n] = __builtin_amdgcn_mfma_f32_16x16x32_bf16(
            as_bf16x8(af[m]), as_bf16x8(bfr[n]), acc[m][n], 0, 0, 0);
    if (t2 < 30)       asm volatile("s_waitcnt vmcnt(4)" ::: "memory");  // tile t2+1 ready
    else if (t2 == 30) asm volatile("s_waitcnt vmcnt(0)" ::: "memory");  // last tile ready
    if (t2 < 31) __builtin_amdgcn_s_barrier();
    int tmp = sl0; sl0 = sl1; sl1 = sl2; sl2 = tmp;
  }
  __builtin_amdgcn_s_barrier();   // all K-loop LDS reads done before smem reuse

  const size_t cb20 = (size_t)bc << 20;

  if (OUT_BF16) {
    // repack through per-wave LDS region -> coalesced 16B bf16 stores (halves HBM write)
    unsigned short* sE = (unsigned short*)smem + wave * 1024;   // 2 KB/wave
    #pragma unroll
    for (int m = 0; m < 4; ++m) {
      #pragma unroll
      for (int n = 0; n < 4; ++n)
        #pragma unroll
        for (int j = 0; j < 4; ++j)
          sE[(ha * 4 + j) * 64 + n * 16 + la] = f2bf(acc[m][n][j]);
      int rrow = lane >> 2;
      int cch  = (lane & 3) * 16;
      u16x8 v0 = *(const u16x8*)&sE[rrow * 64 + cch];
      u16x8 v1 = *(const u16x8*)&sE[rrow * 64 + cch + 8];
      unsigned short* gp = Cbf + cb20 +
          (size_t)(bi * 128 + wr * 64 + m * 16 + rrow) * 1024 + bj * 128 + wc * 64 + cch;
      *(u16x8*)gp = v0;
      *(u16x8*)(gp + 8) = v1;
      __builtin_amdgcn_s_barrier();   // wave-region reuse across m-rounds (cheap, safe)
    }
  } else {
    // direct coalesced f32 write of the computed (upper) tile
    #pragma unroll
    for (int m = 0; m < 4; ++m) {
      int row0 = bi * 128 + wr * 64 + m * 16 + ha * 4;
      #pragma unroll
      for (int n = 0; n < 4; ++n) {
        int col = bj * 128 + wc * 64 + n * 16 + la;
        #pragma unroll
        for (int j = 0; j < 4; ++j)
          Cf[cb20 + (size_t)(row0 + j) * 1024 + col] = acc[m][n][j];
      }
    }
    if (SYMM && bi != bj) {
      // mirror: LDS band transpose (32x128 f32 bands), coalesced f32x4 stores
      float (*sT)[129] = (float(*)[129])smem;    // 32*129*4 = 16.5 KB
      #pragma unroll
      for (int b = 0; b < 4; ++b) {
        if (wr == (b >> 1)) {
          #pragma unroll
          for (int dm = 0; dm < 2; ++dm) {
            int m = (b & 1) * 2 + dm;
            #pragma unroll
            for (int n = 0; n < 4; ++n)
              #pragma unroll
              for (int j = 0; j < 4; ++j)
                sT[dm * 16 + ha * 4 + j][wc * 64 + n * 16 + la] = acc[m][n][j];
          }
        }
        __syncthreads();
        int c  = tid >> 1;
        int r0 = (tid & 1) * 16;
        float* gp = Cf + cb20 + (size_t)(bj * 128 + c) * 1024 + bi * 128 + b * 32 + r0;
        #pragma unroll
        for (int q = 0; q < 4; ++q) {
          f32x4 v;
          #pragma unroll
          for (int k = 0; k < 4; ++k) v[k] = sT[r0 + q * 4 + k][c];
          *(f32x4*)(gp + q * 4) = v;
        }
        __syncthreads();
      }
    }
  }
}

extern "C" void kernel_launch(void* const* d_in, const int* in_sizes, int n_in,
                              void* d_out, int out_size, void* d_ws, size_t ws_size,
                              hipStream_t stream) {
  const float* xz = (const float*)d_in[0];
  const float* z  = (const float*)d_in[1];
  const float* x  = (const float*)d_in[2];
  const float* ls = (const float*)d_in[3];
  float* out = (float*)d_out;

  unsigned short* W  = (unsigned short*)d_ws;          // 8 MB
  unsigned short* Zt = W + ((size_t)4 << 20);          // 64 MB
  unsigned short* z1 = Zt + ((size_t)32 << 20);        // 64 MB

  hipMemcpyAsync(out, xz, 1024 * sizeof(float), hipMemcpyDeviceToDevice, stream);
  weights_kernel<<<4096, 256, 0, stream>>>(xz, x, ls, W);
  transpose_kernel<<<dim3(16, 16, 32), 256, 0, stream>>>(z, Zt);
  gemm_nt<64, true,  true,  false><<<32 * 64, 256, 0, stream>>>(W,  Zt, z1, nullptr);
  gemm_nt<36, false, false, true ><<<32 * 36, 256, 0, stream>>>(z1, z1, nullptr, out + 1024);
}